// Round 1
// baseline (3362.149 us; speedup 1.0000x reference)
//
#include <hip/hip_runtime.h>
#include <hip/hip_bf16.h>

#define VOCAB 50257
#define EMBD  256
#define HID   512
#define BATCH 64
#define SEQ   512

typedef short bf16x8 __attribute__((ext_vector_type(8)));
typedef float f32x4  __attribute__((ext_vector_type(4)));

__device__ inline short f2b(float f) {            // RNE float->bf16
    union { float f; unsigned u; } v; v.f = f;
    unsigned r = v.u + 0x7FFFu + ((v.u >> 16) & 1u);
    return (short)(r >> 16);
}
__device__ inline unsigned pack2_trunc(float lo, float hi) {  // 2 floats -> packed bf16x2 (truncate)
    union { float f; unsigned u; } a, b; a.f = lo; b.f = hi;
    return __builtin_amdgcn_perm(b.u, a.u, 0x07060302);
}
__device__ inline float fast_tanh(float x) {
    x = fminf(fmaxf(x, -15.f), 15.f);
    float e = __expf(2.f * x);
    return (e - 1.f) / (e + 1.f);
}
__device__ inline float fast_sig(float x) { return 1.f / (1.f + __expf(-x)); }

__device__ inline void load_x_frags(const float* __restrict__ emb, int idxv, int quad, bf16x8* Ax) {
#pragma unroll
    for (int kt = 0; kt < 8; ++kt) {
        const float* p = emb + (size_t)idxv * EMBD + kt * 32 + quad * 8;
        float4 e0 = *(const float4*)(p);
        float4 e1 = *(const float4*)(p + 4);
        union { bf16x8 v; unsigned u[4]; } f;
        f.u[0] = pack2_trunc(e0.x, e0.y);
        f.u[1] = pack2_trunc(e0.z, e0.w);
        f.u[2] = pack2_trunc(e1.x, e1.y);
        f.u[3] = pack2_trunc(e1.z, e1.w);
        Ax[kt] = f.v;
    }
}

// ---------------------------------------------------------------------------
// Persistent LSTM: 64 WGs x 512 thr = 4 groups (16 batch rows) x 16 WGs
// (32 h-cols each). grp = wgid&3 -> each group's 16 WGs sit on 2 XCDs under
// round-robin dispatch (perf-only).
//
// GATE-INTERLEAVED columns: wave w owns 4 actual cols x 4 gates as its 16
// MFMA B-columns (B-col l16 -> weight col (l16>>2)*512 + base + (l16&3)).
// After the MFMA, i/f/g/o for one (row,col) sit in lanes cc,cc+4,cc+8,cc+12
// of the same quad -> 3x shfl_xor gathers them and the c/h update is
// WAVE-LOCAL: no gate-exchange LDS buffer, no second barrier, no update-
// thread handoff. c-state lives in the gl==0 lanes' registers.
//
// h exchange: unchanged protocol — self-validating 8B units {step tag,
// 2 x bf16 cols}, ONE relaxed agent atomic store, consumer wave-uniform
// batched tag-poll (8 units/lane, fan-in 16 producer WGs per row).
// hstage is parity double-buffered -> exactly ONE __syncthreads per step
// (protocol's all-to-all bounds inter-WG skew to < 2 steps; intra-WG skew
// is bounded by the single barrier, so buffer parity never collides).
// ---------------------------------------------------------------------------
__global__ __launch_bounds__(512, 2) void lstm_kernel(
    const int* __restrict__ idx, const float* __restrict__ emb,
    const float* __restrict__ Wi, const float* __restrict__ Wh,
    const float* __restrict__ bvec,
    unsigned long long* __restrict__ hbuf /* [2][4][16][256] tagged units */,
    unsigned short* __restrict__ hfinal /* [64][512] bf16 */)
{
    const int wgid = blockIdx.x;       // 64 WGs
    const int grp  = wgid & 3;         // batch group 0..3 (XCD-paired)
    const int jj   = wgid >> 2;        // 0..15: 32-col slice
    const int tid  = threadIdx.x;
    const int lane = tid & 63;
    const int w    = tid >> 6;         // wave 0..7
    const int quad = lane >> 4;
    const int l16  = lane & 15;
    const int gl   = l16 >> 2;         // gate of this B-column (i,f,g,o)
    const int cc   = l16 & 3;          // col within wave's 4
    const int cbase = jj * 32 + w * 4; // first actual col of this wave
    const int colW  = gl * HID + cbase + cc;  // weight column (gate-interleaved)
    const int arow  = grp * 16 + l16;  // batch row for A fragments

    // row stride 520 ush = 1040B = 260 dwords; 260 mod 32 = 4 with odd 65 ->
    // ds_read_b128 16B windows spread evenly over the 8 bank-windows (ideal).
    __shared__ __align__(16) unsigned short hstage[2][16][520];

    // persistent B fragments: Wh k=512, Wi k=256 (RNE converted once)
    bf16x8 Bh[16], Bx[8];
#pragma unroll
    for (int kt = 0; kt < 16; ++kt)
#pragma unroll
        for (int i = 0; i < 8; ++i)
            Bh[kt][i] = f2b(Wh[(size_t)(kt * 32 + quad * 8 + i) * 2048 + colW]);
#pragma unroll
    for (int kt = 0; kt < 8; ++kt)
#pragma unroll
        for (int i = 0; i < 8; ++i)
            Bx[kt][i] = f2b(Wi[(size_t)(kt * 32 + quad * 8 + i) * 2048 + colW]);
    const float bv = bvec[colW];

    bf16x8 Ax[8];
    load_x_frags(emb, idx[arow * SEQ], quad, Ax);

    // consumer staging mapping: wave w owns rows {2w, 2w+1}; 8 units/lane
    const int srow  = w * 2 + (lane >> 5);
    const int sunit = lane & 31;

    // c-state: rows quad*4+r, col cbase+cc (valid in gl==0 lanes)
    float cs[4] = {0.f, 0.f, 0.f, 0.f};

    for (int t = 0; t < SEQ; ++t) {
        const unsigned long long* rbase =
            hbuf + ((size_t)((t & 1) * 4 + grp) * 16 + srow) * 256 + sunit;

        unsigned long long v[8];
        if (t > 0) {   // issue staging loads immediately (overlap x-MFMA)
#pragma unroll
            for (int i = 0; i < 8; ++i)
                v[i] = __hip_atomic_load(rbase + i * 32,
                                         __ATOMIC_RELAXED, __HIP_MEMORY_SCOPE_AGENT);
        }

        // ---- x contribution (Ax prefetched at end of previous step) ----
        f32x4 a0 = {0.f, 0.f, 0.f, 0.f}, a1 = {0.f, 0.f, 0.f, 0.f};
#pragma unroll
        for (int kt = 0; kt < 8; kt += 2) {
            a0 = __builtin_amdgcn_mfma_f32_16x16x32_bf16(Ax[kt],     Bx[kt],     a0, 0, 0, 0);
            a1 = __builtin_amdgcn_mfma_f32_16x16x32_bf16(Ax[kt + 1], Bx[kt + 1], a1, 0, 0, 0);
        }

        if (t > 0) {
            // ---- wave-uniform tag poll: batched reloads, no divergence ----
            const unsigned tg = (unsigned)t;
            while (true) {
                bool ok = true;
#pragma unroll
                for (int i = 0; i < 8; ++i)
                    ok = ok && ((unsigned)(v[i] >> 32) == tg);
                if (__ballot(ok) == ~0ull) break;
#pragma unroll
                for (int i = 0; i < 8; ++i)
                    v[i] = __hip_atomic_load(rbase + i * 32,
                                             __ATOMIC_RELAXED, __HIP_MEMORY_SCOPE_AGENT);
            }
#pragma unroll
            for (int i = 0; i < 8; ++i)
                *(unsigned*)&hstage[t & 1][srow][(sunit + i * 32) * 2] = (unsigned)v[i];
        }
        __syncthreads();   // the ONLY barrier per step: hstage[t&1] ready

        if (t > 0) {
#pragma unroll
            for (int kt = 0; kt < 16; kt += 2) {
                bf16x8 ha = *(const bf16x8*)&hstage[t & 1][l16][kt * 32 + quad * 8];
                bf16x8 hb = *(const bf16x8*)&hstage[t & 1][l16][(kt + 1) * 32 + quad * 8];
                a0 = __builtin_amdgcn_mfma_f32_16x16x32_bf16(ha, Bh[kt],     a0, 0, 0, 0);
                a1 = __builtin_amdgcn_mfma_f32_16x16x32_bf16(hb, Bh[kt + 1], a1, 0, 0, 0);
            }
        }

        // ---- activation + WAVE-LOCAL c/h update ----
        // C layout: row = quad*4+r, B-col = l16 (gate gl of actual col cbase+cc).
        // shfl_xor 4/8/12 brings gates f,g,o to the gl==0 lanes.
        float hreg[4];
#pragma unroll
        for (int r = 0; r < 4; ++r) {
            float z   = a0[r] + a1[r] + bv;
            float act = (gl == 2) ? fast_tanh(z) : fast_sig(z);
            float vf  = __shfl_xor(act, 4);    // gate gl^1 (f for gl==0)
            float vg  = __shfl_xor(act, 8);    // gate gl^2 (g for gl==0)
            float vo  = __shfl_xor(act, 12);   // gate gl^3 (o for gl==0)
            float cn  = vf * cs[r] + act * vg; // valid in gl==0 lanes
            cs[r]     = cn;
            hreg[r]   = vo * fast_tanh(cn);
        }
        // pack adjacent-col pairs: even-cc lane takes odd-cc partner's h
        unsigned pv[4];
#pragma unroll
        for (int r = 0; r < 4; ++r) {
            float ho = __shfl_xor(hreg[r], 1);
            pv[r] = (unsigned)(unsigned short)f2b(hreg[r]) |
                    ((unsigned)(unsigned short)f2b(ho) << 16);
        }

        // ---- tagged 8B stores, fire-and-forget: lanes (gl==0, cc even) ----
        if (gl == 0 && (cc & 1) == 0) {
            const int cp = jj * 16 + w * 2 + (cc >> 1);   // col-pair 0..255
            unsigned long long* dst = hbuf +
                ((size_t)(((t + 1) & 1) * 4 + grp) * 16 + quad * 4) * 256 + cp;
#pragma unroll
            for (int r = 0; r < 4; ++r) {
                unsigned long long val = (unsigned long long)pv[r] |
                                         ((unsigned long long)(unsigned)(t + 1) << 32);
                __hip_atomic_store(dst + (size_t)r * 256, val,
                                   __ATOMIC_RELAXED, __HIP_MEMORY_SCOPE_AGENT);
            }
            if (t == SEQ - 1) {
#pragma unroll
                for (int r = 0; r < 4; ++r)
                    *(unsigned*)&hfinal[(size_t)(grp * 16 + quad * 4 + r) * HID +
                                        cbase + cc] = pv[r];
            }
        }

        // ---- emb prefetch for t+1: drains inside next step's poll wait ----
        if (t + 1 < SEQ) {
            int nx = idx[arow * SEQ + t + 1];
            load_x_frags(emb, nx, quad, Ax);
        }
    }
}

// ---------------------------------------------------------------------------
// y = tanh(A[64x512](bf16) @ W[512x512](f32) + bias) -> out bf16 [64][512]
// ---------------------------------------------------------------------------
__global__ __launch_bounds__(256, 1) void gemm_tanh_kernel(
    const unsigned short* __restrict__ A, const float* __restrict__ W,
    const float* __restrict__ bias, unsigned short* __restrict__ out)
{
    const int tid = threadIdx.x, lane = tid & 63, wave = tid >> 6;
    const int quad = lane >> 4, l16 = lane & 15;
    const int col = blockIdx.x * 16 + l16;
    bf16x8 Bw[16];
#pragma unroll
    for (int kt = 0; kt < 16; ++kt)
#pragma unroll
        for (int i = 0; i < 8; ++i)
            Bw[kt][i] = f2b(W[(size_t)(kt * 32 + quad * 8 + i) * HID + col]);
    f32x4 acc = {0.f, 0.f, 0.f, 0.f};
#pragma unroll
    for (int kt = 0; kt < 16; ++kt) {
        bf16x8 a = *(const bf16x8*)(A + (size_t)(wave * 16 + l16) * HID + kt * 32 + quad * 8);
        acc = __builtin_amdgcn_mfma_f32_16x16x32_bf16(a, Bw[kt], acc, 0, 0, 0);
    }
    const float bvv = bias[col];
#pragma unroll
    for (int r = 0; r < 4; ++r) {
        float y = fast_tanh(acc[r] + bvv);
        out[(size_t)(wave * 16 + quad * 4 + r) * HID + col] = (unsigned short)f2b(y);
    }
}

// ---------------------------------------------------------------------------
// logits = A[64x512](bf16) @ W3[512x50257](f32) + b3 -> f32 [64][50257]
// LDS-staged W3 tiles: coalesced float4 HBM reads.
// ---------------------------------------------------------------------------
__global__ __launch_bounds__(256, 2) void logits_kernel(
    const unsigned short* __restrict__ A, const float* __restrict__ W3,
    const float* __restrict__ b3, float* __restrict__ outL)
{
    const int tid = threadIdx.x, lane = tid & 63, wave = tid >> 6;
    const int quad = lane >> 4, l16 = lane & 15;
    const int c0 = blockIdx.x * 64;
    const int col = c0 + wave * 16 + l16;
    const bool cok = col < VOCAB;
    const int colc = cok ? col : (VOCAB - 1);

    __shared__ unsigned short wt[256][68];

    f32x4 acc[4];
#pragma unroll
    for (int rt = 0; rt < 4; ++rt) acc[rt] = (f32x4){0.f, 0.f, 0.f, 0.f};

    const int kr = tid >> 4;
    const int cg = (tid & 15) * 4;

    for (int kc = 0; kc < 2; ++kc) {
#pragma unroll 4
        for (int it = 0; it < 16; ++it) {
            const int k = it * 16 + kr;
            const int gc = c0 + cg;
            float4 wv;
            if (gc + 3 < VOCAB) {
                wv = *(const float4*)&W3[(size_t)(kc * 256 + k) * VOCAB + gc];
            } else {
                const float* Wr = &W3[(size_t)(kc * 256 + k) * VOCAB];
                wv.x = (gc + 0 < VOCAB) ? Wr[gc + 0] : 0.f;
                wv.y = (gc + 1 < VOCAB) ? Wr[gc + 1] : 0.f;
                wv.z = (gc + 2 < VOCAB) ? Wr[gc + 2] : 0.f;
                wv.w = (gc + 3 < VOCAB) ? Wr[gc + 3] : 0.f;
            }
            unsigned short* d = &wt[k][cg];
            d[0] = (unsigned short)f2b(wv.x);
            d[1] = (unsigned short)f2b(wv.y);
            d[2] = (unsigned short)f2b(wv.z);
            d[3] = (unsigned short)f2b(wv.w);
        }
        __syncthreads();
        bf16x8 Bw[8];
#pragma unroll
        for (int kt = 0; kt < 8; ++kt)
#pragma unroll
            for (int i = 0; i < 8; ++i)
                Bw[kt][i] = (short)wt[kt * 32 + quad * 8 + i][wave * 16 + l16];
#pragma unroll
        for (int rt = 0; rt < 4; ++rt)
#pragma unroll
            for (int kt = 0; kt < 8; ++kt) {
                bf16x8 a = *(const bf16x8*)(A + (size_t)(rt * 16 + l16) * HID +
                                            kc * 256 + kt * 32 + quad * 8);
                acc[rt] = __builtin_amdgcn_mfma_f32_16x16x32_bf16(a, Bw[kt], acc[rt], 0, 0, 0);
            }
        __syncthreads();
    }
    const float bvv = b3[colc];
    if (cok) {
#pragma unroll
        for (int rt = 0; rt < 4; ++rt)
#pragma unroll
            for (int r = 0; r < 4; ++r)
                outL[(size_t)(rt * 16 + quad * 4 + r) * VOCAB + col] = acc[rt][r] + bvv;
    }
}

// ---------------------------------------------------------------------------
// row-wise log_softmax over [64][50257], float4 main loop
// ---------------------------------------------------------------------------
__global__ __launch_bounds__(256, 1) void lsm_kernel(
    const float* __restrict__ lg, float* __restrict__ out)
{
    const int row = blockIdx.x;
    const float* L = lg + (size_t)row * VOCAB;
    const float4* L4 = (const float4*)L;
    const int nv4 = VOCAB / 4;

    float m = -1e30f;
    for (int i = threadIdx.x; i < nv4; i += 256) {
        float4 v = L4[i];
        m = fmaxf(fmaxf(fmaxf(m, v.x), fmaxf(v.y, v.z)), v.w);
    }
    if (threadIdx.x == 0) m = fmaxf(m, L[VOCAB - 1]);
#pragma unroll
    for (int o = 32; o; o >>= 1) m = fmaxf(m, __shfl_xor(m, o));
    __shared__ float red[4], red2[4];
    if ((threadIdx.x & 63) == 0) red[threadIdx.x >> 6] = m;
    __syncthreads();
    m = fmaxf(fmaxf(red[0], red[1]), fmaxf(red[2], red[3]));

    float s = 0.f;
    for (int i = threadIdx.x; i < nv4; i += 256) {
        float4 v = L4[i];
        s += __expf(v.x - m) + __expf(v.y - m) + __expf(v.z - m) + __expf(v.w - m);
    }
    if (threadIdx.x == 0) s += __expf(L[VOCAB - 1] - m);
#pragma unroll
    for (int o = 32; o; o >>= 1) s += __shfl_xor(s, o);
    if ((threadIdx.x & 63) == 0) red2[threadIdx.x >> 6] = s;
    __syncthreads();
    s = red2[0] + red2[1] + red2[2] + red2[3];
    const float ls = m + __logf(s);

    float* O = out + (size_t)row * VOCAB;
    float4* O4 = (float4*)O;
    for (int i = threadIdx.x; i < nv4; i += 256) {
        float4 v = L4[i];
        O4[i] = (float4){v.x - ls, v.y - ls, v.z - ls, v.w - ls};
    }
    if (threadIdx.x == 0) O[VOCAB - 1] = L[VOCAB - 1] - ls;
}

extern "C" void kernel_launch(void* const* d_in, const int* in_sizes, int n_in,
                              void* d_out, int out_size, void* d_ws, size_t ws_size,
                              hipStream_t stream) {
    (void)in_sizes; (void)n_in; (void)out_size; (void)ws_size;
    const int*   idx = (const int*)d_in[0];
    const float* emb = (const float*)d_in[1];
    const float* Wi  = (const float*)d_in[2];
    const float* Wh  = (const float*)d_in[3];
    const float* b   = (const float*)d_in[4];
    const float* W1  = (const float*)d_in[5];
    const float* b1  = (const float*)d_in[6];
    const float* W2  = (const float*)d_in[7];
    const float* b2  = (const float*)d_in[8];
    const float* W3  = (const float*)d_in[9];
    const float* b3  = (const float*)d_in[10];
    float* out = (float*)d_out;

    // ws layout (time-disjoint aliasing, 13.13 MB total):
    //   [0, 256K)           hbuf   (lstm only) -- later reused by y1/y2
    //   [0, 64K)            y1     (gemm1 out / gemm2 in)
    //   [64K, 128K)         y2     (gemm2 out / logits in)
    //   [256K, 320K)        hfinal (lstm out / gemm1 in) -- dead before logits writes
    //   [256K, 256K+12.87M) logits (logits out / lsm in)
    char* w = (char*)d_ws;
    unsigned long long* hbuf   = (unsigned long long*)w;
    unsigned short*     y1     = (unsigned short*)w;
    unsigned short*     y2     = (unsigned short*)(w + 65536);
    unsigned short*     hfinal = (unsigned short*)(w + 262144);
    float*              logits = (float*)(w + 262144);

    lstm_kernel<<<64, 512, 0, stream>>>(idx, emb, Wi, Wh, b, hbuf, hfinal);
    gemm_tanh_kernel<<<HID / 16, 256, 0, stream>>>(hfinal, W1, b1, y1);
    gemm_tanh_kernel<<<HID / 16, 256, 0, stream>>>(y1, W2, b2, y2);
    logits_kernel<<<(VOCAB + 63) / 64, 256, 0, stream>>>(y2, W3, b3, logits);
    lsm_kernel<<<BATCH, 256, 0, stream>>>(logits, out);
}

// Round 2
// 2324.030 us; speedup vs baseline: 1.4467x; 1.4467x over previous
//
#include <hip/hip_runtime.h>
#include <hip/hip_bf16.h>

#define VOCAB 50257
#define EMBD  256
#define HID   512
#define BATCH 64
#define SEQ   512

typedef short bf16x8 __attribute__((ext_vector_type(8)));
typedef float f32x4  __attribute__((ext_vector_type(4)));

__device__ inline short f2b(float f) {            // RNE float->bf16
    union { float f; unsigned u; } v; v.f = f;
    unsigned r = v.u + 0x7FFFu + ((v.u >> 16) & 1u);
    return (short)(r >> 16);
}
__device__ inline unsigned pack2_trunc(float lo, float hi) {  // 2 floats -> packed bf16x2 (truncate)
    union { float f; unsigned u; } a, b; a.f = lo; b.f = hi;
    return __builtin_amdgcn_perm(b.u, a.u, 0x07060302);
}
__device__ inline float fast_tanh(float x) {
    x = fminf(fmaxf(x, -15.f), 15.f);
    float e = __expf(2.f * x);
    return (e - 1.f) / (e + 1.f);
}
__device__ inline float fast_sig(float x) { return 1.f / (1.f + __expf(-x)); }

__device__ inline void load_x_frags(const float* __restrict__ emb, int idxv, int quad, bf16x8* Ax) {
#pragma unroll
    for (int kt = 0; kt < 8; ++kt) {
        const float* p = emb + (size_t)idxv * EMBD + kt * 32 + quad * 8;
        float4 e0 = *(const float4*)(p);
        float4 e1 = *(const float4*)(p + 4);
        union { bf16x8 v; unsigned u[4]; } f;
        f.u[0] = pack2_trunc(e0.x, e0.y);
        f.u[1] = pack2_trunc(e0.z, e0.w);
        f.u[2] = pack2_trunc(e1.x, e1.y);
        f.u[3] = pack2_trunc(e1.z, e1.w);
        Ax[kt] = f.v;
    }
}

// ---------------------------------------------------------------------------
// Persistent LSTM: 128 WGs x 256 thr = 4 groups (16 batch rows, grp=wgid>>5,
// proven r0 mapping) x 32 WGs (16 h-cols each). Wave w owns 4 actual cols.
//
// SWAPPED-OPERAND MFMA (z^T): A = transposed weight slice (16 "slots" x K),
// B = x^T / h^T. Per-lane B-fragment bytes for h/x are IDENTICAL to the old
// A-fragment bytes (A<->B^T duality) -> hstage/Ax loads unchanged from r0.
// Slot index rho = quad*4+r maps to (gate = r, colofs = quad), so the C
// layout (row=quad*4+r, col=lane&15=batch row) puts ALL FOUR GATES of one
// (batch,col) cell into one lane's acc[0..3]:
//   lane (l16,quad): acc[r] = z(batch=l16, col=cbase+quad, gate=r)
// -> LSTM update is fully LANE-LOCAL (1 cell/lane, 64 cells/wave). No gate
// LDS buffer, no second barrier, no update-wave handoff, ONE col-pair shfl.
//
// h exchange protocol r0-verbatim: tagged 8B units {step tag, 2 x bf16},
// relaxed agent atomics, wave-uniform batched tag poll (wave w polls rows
// w*4+quad, 16 units/lane). hstage parity double-buffered -> ONE barrier
// per step (a wave stages t+1 only after poll(t+1), which requires all
// stores of t+1, which requires every wave passed this WG's barrier(t) --
// so no wave can still be reading parity t&1 when it is overwritten).
// ---------------------------------------------------------------------------
__global__ __launch_bounds__(256, 1) void lstm_kernel(
    const int* __restrict__ idx, const float* __restrict__ emb,
    const float* __restrict__ Wi, const float* __restrict__ Wh,
    const float* __restrict__ bvec,
    unsigned long long* __restrict__ hbuf /* [2][4][16][256] tagged units */,
    unsigned short* __restrict__ hfinal /* [64][512] bf16 */)
{
    const int wgid = blockIdx.x;       // 128 WGs
    const int grp  = wgid >> 5;        // batch group 0..3
    const int jj   = wgid & 31;        // 16-col slice
    const int tid  = threadIdx.x;
    const int lane = tid & 63;
    const int w    = tid >> 6;         // wave 0..3
    const int quad = lane >> 4;
    const int l16  = lane & 15;
    const int cbase = jj * 16 + w * 4;            // first of wave's 4 cols
    // A-fragment weight column for A-row (slot) = l16: gate = l16&3, colofs = l16>>2
    const int wcol  = (l16 & 3) * HID + cbase + (l16 >> 2);
    const int arow  = grp * 16 + l16;  // batch row for B(x/h) fragments

    __shared__ __align__(16) unsigned short hstage[2][16][520];  // stride 1040B

    // persistent A fragments (transposed weights): Wh k=512, Wi k=256
    bf16x8 Bh[16], Bx[8];
#pragma unroll
    for (int kt = 0; kt < 16; ++kt)
#pragma unroll
        for (int i = 0; i < 8; ++i)
            Bh[kt][i] = f2b(Wh[(size_t)(kt * 32 + quad * 8 + i) * 2048 + wcol]);
#pragma unroll
    for (int kt = 0; kt < 8; ++kt)
#pragma unroll
        for (int i = 0; i < 8; ++i)
            Bx[kt][i] = f2b(Wi[(size_t)(kt * 32 + quad * 8 + i) * 2048 + wcol]);

    // per-lane bias: 4 gates of col cbase+quad
    float bvr[4];
#pragma unroll
    for (int r = 0; r < 4; ++r) bvr[r] = bvec[r * HID + cbase + quad];

    bf16x8 Ax[8];
    load_x_frags(emb, idx[arow * SEQ], quad, Ax);

    // consumer staging mapping (r0-verbatim): wave w owns rows w*4+quad
    const int srow = w * 4 + quad;

    // one c-cell per lane: (batch=l16, col=cbase+quad)
    float cs = 0.f;

    for (int t = 0; t < SEQ; ++t) {
        const unsigned long long* rbase =
            hbuf + ((size_t)((t & 1) * 4 + grp) * 16 + srow) * 256 + l16;

        unsigned long long v[16];
        if (t > 0) {   // issue staging loads immediately (overlap x-MFMA)
#pragma unroll
            for (int i = 0; i < 16; ++i)
                v[i] = __hip_atomic_load(rbase + i * 16,
                                         __ATOMIC_RELAXED, __HIP_MEMORY_SCOPE_AGENT);
        }

        // ---- x contribution: A=Wi^T-slots, B=x (Ax prefetched last step) ----
        f32x4 a0 = {0.f, 0.f, 0.f, 0.f}, a1 = {0.f, 0.f, 0.f, 0.f};
#pragma unroll
        for (int kt = 0; kt < 8; kt += 2) {
            a0 = __builtin_amdgcn_mfma_f32_16x16x32_bf16(Bx[kt],     Ax[kt],     a0, 0, 0, 0);
            a1 = __builtin_amdgcn_mfma_f32_16x16x32_bf16(Bx[kt + 1], Ax[kt + 1], a1, 0, 0, 0);
        }

        if (t > 0) {
            // ---- wave-uniform tag poll: batched reloads, no divergence ----
            const unsigned tg = (unsigned)t;
            while (true) {
                bool ok = true;
#pragma unroll
                for (int i = 0; i < 16; ++i)
                    ok = ok && ((unsigned)(v[i] >> 32) == tg);
                if (__ballot(ok) == ~0ull) break;
#pragma unroll
                for (int i = 0; i < 16; ++i)
                    v[i] = __hip_atomic_load(rbase + i * 16,
                                             __ATOMIC_RELAXED, __HIP_MEMORY_SCOPE_AGENT);
            }
#pragma unroll
            for (int i = 0; i < 16; ++i)
                *(unsigned*)&hstage[t & 1][srow][(l16 + i * 16) * 2] = (unsigned)v[i];
        }
        __syncthreads();   // the ONLY barrier per step: hstage[t&1] ready

        if (t > 0) {
#pragma unroll
            for (int kt = 0; kt < 16; kt += 2) {
                bf16x8 ha = *(const bf16x8*)&hstage[t & 1][l16][kt * 32 + quad * 8];
                bf16x8 hb = *(const bf16x8*)&hstage[t & 1][l16][(kt + 1) * 32 + quad * 8];
                a0 = __builtin_amdgcn_mfma_f32_16x16x32_bf16(Bh[kt],     ha, a0, 0, 0, 0);
                a1 = __builtin_amdgcn_mfma_f32_16x16x32_bf16(Bh[kt + 1], hb, a1, 0, 0, 0);
            }
        }

        // ---- fully lane-local activation + c/h update (no divergence) ----
        float iG = fast_sig (a0[0] + a1[0] + bvr[0]);
        float fG = fast_sig (a0[1] + a1[1] + bvr[1]);
        float gG = fast_tanh(a0[2] + a1[2] + bvr[2]);
        float oG = fast_sig (a0[3] + a1[3] + bvr[3]);
        cs = fG * cs + iG * gG;
        float h  = oG * fast_tanh(cs);
        float hp = __shfl_xor(h, 16);            // partner col (quad^1)
        unsigned pv = (unsigned)(unsigned short)f2b(h) |
                      ((unsigned)(unsigned short)f2b(hp) << 16);

        // ---- tagged 8B store, fire-and-forget: even-quad lanes (32/wave) ----
        if ((quad & 1) == 0) {
            const int cp = jj * 8 + w * 2 + (quad >> 1);   // col-pair 0..255
            unsigned long long val = (unsigned long long)pv |
                                     ((unsigned long long)(unsigned)(t + 1) << 32);
            unsigned long long* dst = hbuf +
                ((size_t)(((t + 1) & 1) * 4 + grp) * 16 + l16) * 256 + cp;
            __hip_atomic_store(dst, val, __ATOMIC_RELAXED, __HIP_MEMORY_SCOPE_AGENT);
            if (t == SEQ - 1)
                *(unsigned*)&hfinal[(size_t)(grp * 16 + l16) * HID + cbase + quad] = pv;
        }

        // ---- emb prefetch for t+1: drains inside next step's poll wait ----
        if (t + 1 < SEQ) {
            int nx = idx[arow * SEQ + t + 1];
            load_x_frags(emb, nx, quad, Ax);
        }
    }
}

// ---------------------------------------------------------------------------
// y = tanh(A[64x512](bf16) @ W[512x512](f32) + bias) -> out bf16 [64][512]
// ---------------------------------------------------------------------------
__global__ __launch_bounds__(256, 1) void gemm_tanh_kernel(
    const unsigned short* __restrict__ A, const float* __restrict__ W,
    const float* __restrict__ bias, unsigned short* __restrict__ out)
{
    const int tid = threadIdx.x, lane = tid & 63, wave = tid >> 6;
    const int quad = lane >> 4, l16 = lane & 15;
    const int col = blockIdx.x * 16 + l16;
    bf16x8 Bw[16];
#pragma unroll
    for (int kt = 0; kt < 16; ++kt)
#pragma unroll
        for (int i = 0; i < 8; ++i)
            Bw[kt][i] = f2b(W[(size_t)(kt * 32 + quad * 8 + i) * HID + col]);
    f32x4 acc = {0.f, 0.f, 0.f, 0.f};
#pragma unroll
    for (int kt = 0; kt < 16; ++kt) {
        bf16x8 a = *(const bf16x8*)(A + (size_t)(wave * 16 + l16) * HID + kt * 32 + quad * 8);
        acc = __builtin_amdgcn_mfma_f32_16x16x32_bf16(a, Bw[kt], acc, 0, 0, 0);
    }
    const float bvv = bias[col];
#pragma unroll
    for (int r = 0; r < 4; ++r) {
        float y = fast_tanh(acc[r] + bvv);
        out[(size_t)(wave * 16 + quad * 4 + r) * HID + col] = (unsigned short)f2b(y);
    }
}

// ---------------------------------------------------------------------------
// logits = A[64x512](bf16) @ W3[512x50257](f32) + b3 -> f32 [64][50257]
// LDS-staged W3 tiles: coalesced float4 HBM reads.
// ---------------------------------------------------------------------------
__global__ __launch_bounds__(256, 2) void logits_kernel(
    const unsigned short* __restrict__ A, const float* __restrict__ W3,
    const float* __restrict__ b3, float* __restrict__ outL)
{
    const int tid = threadIdx.x, lane = tid & 63, wave = tid >> 6;
    const int quad = lane >> 4, l16 = lane & 15;
    const int c0 = blockIdx.x * 64;
    const int col = c0 + wave * 16 + l16;
    const bool cok = col < VOCAB;
    const int colc = cok ? col : (VOCAB - 1);

    __shared__ unsigned short wt[256][68];

    f32x4 acc[4];
#pragma unroll
    for (int rt = 0; rt < 4; ++rt) acc[rt] = (f32x4){0.f, 0.f, 0.f, 0.f};

    const int kr = tid >> 4;
    const int cg = (tid & 15) * 4;

    for (int kc = 0; kc < 2; ++kc) {
#pragma unroll 4
        for (int it = 0; it < 16; ++it) {
            const int k = it * 16 + kr;
            const int gc = c0 + cg;
            float4 wv;
            if (gc + 3 < VOCAB) {
                wv = *(const float4*)&W3[(size_t)(kc * 256 + k) * VOCAB + gc];
            } else {
                const float* Wr = &W3[(size_t)(kc * 256 + k) * VOCAB];
                wv.x = (gc + 0 < VOCAB) ? Wr[gc + 0] : 0.f;
                wv.y = (gc + 1 < VOCAB) ? Wr[gc + 1] : 0.f;
                wv.z = (gc + 2 < VOCAB) ? Wr[gc + 2] : 0.f;
                wv.w = (gc + 3 < VOCAB) ? Wr[gc + 3] : 0.f;
            }
            unsigned short* d = &wt[k][cg];
            d[0] = (unsigned short)f2b(wv.x);
            d[1] = (unsigned short)f2b(wv.y);
            d[2] = (unsigned short)f2b(wv.z);
            d[3] = (unsigned short)f2b(wv.w);
        }
        __syncthreads();
        bf16x8 Bw[8];
#pragma unroll
        for (int kt = 0; kt < 8; ++kt)
#pragma unroll
            for (int i = 0; i < 8; ++i)
                Bw[kt][i] = (short)wt[kt * 32 + quad * 8 + i][wave * 16 + l16];
#pragma unroll
        for (int rt = 0; rt < 4; ++rt)
#pragma unroll
            for (int kt = 0; kt < 8; ++kt) {
                bf16x8 a = *(const bf16x8*)(A + (size_t)(rt * 16 + l16) * HID +
                                            kc * 256 + kt * 32 + quad * 8);
                acc[rt] = __builtin_amdgcn_mfma_f32_16x16x32_bf16(a, Bw[kt], acc[rt], 0, 0, 0);
            }
        __syncthreads();
    }
    const float bvv = b3[colc];
    if (cok) {
#pragma unroll
        for (int rt = 0; rt < 4; ++rt)
#pragma unroll
            for (int r = 0; r < 4; ++r)
                outL[(size_t)(rt * 16 + quad * 4 + r) * VOCAB + col] = acc[rt][r] + bvv;
    }
}

// ---------------------------------------------------------------------------
// row-wise log_softmax over [64][50257], float4 main loop
// ---------------------------------------------------------------------------
__global__ __launch_bounds__(256, 1) void lsm_kernel(
    const float* __restrict__ lg, float* __restrict__ out)
{
    const int row = blockIdx.x;
    const float* L = lg + (size_t)row * VOCAB;
    const float4* L4 = (const float4*)L;
    const int nv4 = VOCAB / 4;

    float m = -1e30f;
    for (int i = threadIdx.x; i < nv4; i += 256) {
        float4 v = L4[i];
        m = fmaxf(fmaxf(fmaxf(m, v.x), fmaxf(v.y, v.z)), v.w);
    }
    if (threadIdx.x == 0) m = fmaxf(m, L[VOCAB - 1]);
#pragma unroll
    for (int o = 32; o; o >>= 1) m = fmaxf(m, __shfl_xor(m, o));
    __shared__ float red[4], red2[4];
    if ((threadIdx.x & 63) == 0) red[threadIdx.x >> 6] = m;
    __syncthreads();
    m = fmaxf(fmaxf(red[0], red[1]), fmaxf(red[2], red[3]));

    float s = 0.f;
    for (int i = threadIdx.x; i < nv4; i += 256) {
        float4 v = L4[i];
        s += __expf(v.x - m) + __expf(v.y - m) + __expf(v.z - m) + __expf(v.w - m);
    }
    if (threadIdx.x == 0) s += __expf(L[VOCAB - 1] - m);
#pragma unroll
    for (int o = 32; o; o >>= 1) s += __shfl_xor(s, o);
    if ((threadIdx.x & 63) == 0) red2[threadIdx.x >> 6] = s;
    __syncthreads();
    s = red2[0] + red2[1] + red2[2] + red2[3];
    const float ls = m + __logf(s);

    float* O = out + (size_t)row * VOCAB;
    float4* O4 = (float4*)O;
    for (int i = threadIdx.x; i < nv4; i += 256) {
        float4 v = L4[i];
        O4[i] = (float4){v.x - ls, v.y - ls, v.z - ls, v.w - ls};
    }
    if (threadIdx.x == 0) O[VOCAB - 1] = L[VOCAB - 1] - ls;
}

extern "C" void kernel_launch(void* const* d_in, const int* in_sizes, int n_in,
                              void* d_out, int out_size, void* d_ws, size_t ws_size,
                              hipStream_t stream) {
    (void)in_sizes; (void)n_in; (void)out_size; (void)ws_size;
    const int*   idx = (const int*)d_in[0];
    const float* emb = (const float*)d_in[1];
    const float* Wi  = (const float*)d_in[2];
    const float* Wh  = (const float*)d_in[3];
    const float* b   = (const float*)d_in[4];
    const float* W1  = (const float*)d_in[5];
    const float* b1  = (const float*)d_in[6];
    const float* W2  = (const float*)d_in[7];
    const float* b2  = (const float*)d_in[8];
    const float* W3  = (const float*)d_in[9];
    const float* b3  = (const float*)d_in[10];
    float* out = (float*)d_out;

    // ws layout (time-disjoint aliasing, 13.13 MB total):
    //   [0, 256K)           hbuf   (lstm only) -- later reused by y1/y2
    //   [0, 64K)            y1     (gemm1 out / gemm2 in)
    //   [64K, 128K)         y2     (gemm2 out / logits in)
    //   [256K, 320K)        hfinal (lstm out / gemm1 in) -- dead before logits writes
    //   [256K, 256K+12.87M) logits (logits out / lsm in)
    char* w = (char*)d_ws;
    unsigned long long* hbuf   = (unsigned long long*)w;
    unsigned short*     y1     = (unsigned short*)w;
    unsigned short*     y2     = (unsigned short*)(w + 65536);
    unsigned short*     hfinal = (unsigned short*)(w + 262144);
    float*              logits = (float*)(w + 262144);

    lstm_kernel<<<128, 256, 0, stream>>>(idx, emb, Wi, Wh, b, hbuf, hfinal);
    gemm_tanh_kernel<<<HID / 16, 256, 0, stream>>>(hfinal, W1, b1, y1);
    gemm_tanh_kernel<<<HID / 16, 256, 0, stream>>>(y1, W2, b2, y2);
    logits_kernel<<<(VOCAB + 63) / 64, 256, 0, stream>>>(y2, W3, b3, logits);
    lsm_kernel<<<BATCH, 256, 0, stream>>>(logits, out);
}

// Round 3
// 2217.636 us; speedup vs baseline: 1.5161x; 1.0480x over previous
//
#include <hip/hip_runtime.h>
#include <hip/hip_bf16.h>

#define VOCAB 50257
#define EMBD  256
#define HID   512
#define BATCH 64
#define SEQ   512

typedef short bf16x8 __attribute__((ext_vector_type(8)));
typedef float f32x4  __attribute__((ext_vector_type(4)));

__device__ inline short f2b(float f) {            // RNE float->bf16
    union { float f; unsigned u; } v; v.f = f;
    unsigned r = v.u + 0x7FFFu + ((v.u >> 16) & 1u);
    return (short)(r >> 16);
}
__device__ inline unsigned pack2_trunc(float lo, float hi) {  // 2 floats -> packed bf16x2 (truncate)
    union { float f; unsigned u; } a, b; a.f = lo; b.f = hi;
    return __builtin_amdgcn_perm(b.u, a.u, 0x07060302);
}
__device__ inline float fast_tanh(float x) {
    x = fminf(fmaxf(x, -15.f), 15.f);
    float e = __expf(2.f * x);
    return (e - 1.f) / (e + 1.f);
}
__device__ inline float fast_sig(float x) { return 1.f / (1.f + __expf(-x)); }

__device__ inline void load_x_frags(const float* __restrict__ emb, int idxv, int quad, bf16x8* Ax) {
#pragma unroll
    for (int kt = 0; kt < 8; ++kt) {
        const float* p = emb + (size_t)idxv * EMBD + kt * 32 + quad * 8;
        float4 e0 = *(const float4*)(p);
        float4 e1 = *(const float4*)(p + 4);
        union { bf16x8 v; unsigned u[4]; } f;
        f.u[0] = pack2_trunc(e0.x, e0.y);
        f.u[1] = pack2_trunc(e0.z, e0.w);
        f.u[2] = pack2_trunc(e1.x, e1.y);
        f.u[3] = pack2_trunc(e1.z, e1.w);
        Ax[kt] = f.v;
    }
}

// ---------------------------------------------------------------------------
// Persistent LSTM, r2 structure (128 WGs x 4 waves, swapped-operand MFMA,
// lane-local c/h update) with FRAGMENT-ORDERED h exchange.
//
// Unit index bijection (16 batch x 256 colpairs -> 0..4095):
//   u = D(batch,cp) = (cp>>4)*256 + ((cp>>2)&3)*64 + batch*4 + (cp&3)
// which is exactly the dword order the swapped-MFMA B-fragment reads:
//   fragment read kt, lane L: dwords [kt*256 + L*4 .. +3]   (contiguous 1KB
//   per wave -> ZERO bank conflicts, identical addr across the 4 waves)
// hbuf stores unit u at offset u -> consumer polls are lane-consecutive
// (8 cache lines per load instr instead of 64 -> 8x poll fabric traffic cut)
// and staging LDS writes are consecutive dwords (conflict-free).
//
// Protocol unchanged from r2 (proven): tagged 8B units {tag t+1, 2xbf16},
// relaxed agent atomics, wave-uniform batched tag poll, parity
// double-buffered hstage, ONE barrier per step (skew-bound < 2 steps).
// ---------------------------------------------------------------------------
__global__ __launch_bounds__(256, 1) void lstm_kernel(
    const int* __restrict__ idx, const float* __restrict__ emb,
    const float* __restrict__ Wi, const float* __restrict__ Wh,
    const float* __restrict__ bvec,
    unsigned long long* __restrict__ hbuf /* [2][4][4096] fragment-ordered units */,
    unsigned short* __restrict__ hfinal /* [64][512] bf16 */)
{
    const int wgid = blockIdx.x;       // 128 WGs
    const int grp  = wgid >> 5;        // batch group 0..3
    const int jj   = wgid & 31;        // 16-col slice
    const int tid  = threadIdx.x;
    const int lane = tid & 63;
    const int w    = tid >> 6;         // wave 0..3
    const int quad = lane >> 4;
    const int l16  = lane & 15;
    const int cbase = jj * 16 + w * 4;            // first of wave's 4 cols
    // A-fragment weight column for A-row (slot) = l16: gate = l16&3, colofs = l16>>2
    const int wcol  = (l16 & 3) * HID + cbase + (l16 >> 2);
    const int arow  = grp * 16 + l16;  // batch row for B(x/h) fragments

    __shared__ __align__(16) unsigned hstageF[2][4096];  // fragment-ordered dwords

    // persistent A fragments (transposed weights): Wh k=512, Wi k=256
    bf16x8 Bh[16], Bx[8];
#pragma unroll
    for (int kt = 0; kt < 16; ++kt)
#pragma unroll
        for (int i = 0; i < 8; ++i)
            Bh[kt][i] = f2b(Wh[(size_t)(kt * 32 + quad * 8 + i) * 2048 + wcol]);
#pragma unroll
    for (int kt = 0; kt < 8; ++kt)
#pragma unroll
        for (int i = 0; i < 8; ++i)
            Bx[kt][i] = f2b(Wi[(size_t)(kt * 32 + quad * 8 + i) * 2048 + wcol]);

    // per-lane bias: 4 gates of col cbase+quad
    float bvr[4];
#pragma unroll
    for (int r = 0; r < 4; ++r) bvr[r] = bvec[r * HID + cbase + quad];

    bf16x8 Ax[8];
    load_x_frags(emb, idx[arow * SEQ], quad, Ax);

    // producer store unit: batch = l16, colpair cp = jj*8 + w*2 + (quad>>1)
    const int scp = jj * 8 + w * 2 + (quad >> 1);
    const int su  = (scp >> 4) * 256 + ((scp >> 2) & 3) * 64 + l16 * 4 + (scp & 3);

    // one c-cell per lane: (batch=l16, col=cbase+quad)
    float cs = 0.f;

    for (int t = 0; t < SEQ; ++t) {
        // consumer: wave w stages contiguous dwords [w*1024, w*1024+1024)
        const unsigned long long* rbase =
            hbuf + ((size_t)((t & 1) * 4 + grp) * 4096 + w * 1024 + lane);

        unsigned long long v[16];
        if (t > 0) {   // issue staging loads immediately (overlap x-MFMA)
#pragma unroll
            for (int i = 0; i < 16; ++i)
                v[i] = __hip_atomic_load(rbase + i * 64,
                                         __ATOMIC_RELAXED, __HIP_MEMORY_SCOPE_AGENT);
        }

        // ---- x contribution: A=Wi^T-slots, B=x (Ax prefetched last step) ----
        f32x4 a0 = {0.f, 0.f, 0.f, 0.f}, a1 = {0.f, 0.f, 0.f, 0.f};
#pragma unroll
        for (int kt = 0; kt < 8; kt += 2) {
            a0 = __builtin_amdgcn_mfma_f32_16x16x32_bf16(Bx[kt],     Ax[kt],     a0, 0, 0, 0);
            a1 = __builtin_amdgcn_mfma_f32_16x16x32_bf16(Bx[kt + 1], Ax[kt + 1], a1, 0, 0, 0);
        }

        if (t > 0) {
            // ---- wave-uniform tag poll: batched reloads, no divergence ----
            const unsigned tg = (unsigned)t;
            while (true) {
                bool ok = true;
#pragma unroll
                for (int i = 0; i < 16; ++i)
                    ok = ok && ((unsigned)(v[i] >> 32) == tg);
                if (__ballot(ok) == ~0ull) break;
#pragma unroll
                for (int i = 0; i < 16; ++i)
                    v[i] = __hip_atomic_load(rbase + i * 64,
                                             __ATOMIC_RELAXED, __HIP_MEMORY_SCOPE_AGENT);
            }
            // conflict-free consecutive-dword staging writes
#pragma unroll
            for (int i = 0; i < 16; ++i)
                hstageF[t & 1][w * 1024 + i * 64 + lane] = (unsigned)v[i];
        }
        __syncthreads();   // the ONLY barrier per step: hstageF[t&1] ready

        if (t > 0) {
            const unsigned* hp = &hstageF[t & 1][0];
#pragma unroll
            for (int kt = 0; kt < 16; kt += 2) {
                bf16x8 ha = *(const bf16x8*)(hp + kt * 256 + lane * 4);
                bf16x8 hb = *(const bf16x8*)(hp + (kt + 1) * 256 + lane * 4);
                a0 = __builtin_amdgcn_mfma_f32_16x16x32_bf16(Bh[kt],     ha, a0, 0, 0, 0);
                a1 = __builtin_amdgcn_mfma_f32_16x16x32_bf16(Bh[kt + 1], hb, a1, 0, 0, 0);
            }
        }

        // ---- fully lane-local activation + c/h update (no divergence) ----
        float iG = fast_sig (a0[0] + a1[0] + bvr[0]);
        float fG = fast_sig (a0[1] + a1[1] + bvr[1]);
        float gG = fast_tanh(a0[2] + a1[2] + bvr[2]);
        float oG = fast_sig (a0[3] + a1[3] + bvr[3]);
        cs = fG * cs + iG * gG;
        float h  = oG * fast_tanh(cs);
        float hp2 = __shfl_xor(h, 16);           // partner col (quad^1)
        unsigned pv = (unsigned)(unsigned short)f2b(h) |
                      ((unsigned)(unsigned short)f2b(hp2) << 16);

        // ---- tagged 8B store, fire-and-forget: even-quad lanes (32/wave) ----
        if ((quad & 1) == 0) {
            unsigned long long val = (unsigned long long)pv |
                                     ((unsigned long long)(unsigned)(t + 1) << 32);
            unsigned long long* dst = hbuf +
                ((size_t)(((t + 1) & 1) * 4 + grp) * 4096 + su);
            __hip_atomic_store(dst, val, __ATOMIC_RELAXED, __HIP_MEMORY_SCOPE_AGENT);
            if (t == SEQ - 1)
                *(unsigned*)&hfinal[(size_t)(grp * 16 + l16) * HID + cbase + quad] = pv;
        }

        // ---- emb prefetch for t+1: drains inside next step's poll wait ----
        if (t + 1 < SEQ) {
            int nx = idx[arow * SEQ + t + 1];
            load_x_frags(emb, nx, quad, Ax);
        }
    }
}

// ---------------------------------------------------------------------------
// y = tanh(A[64x512](bf16) @ W[512x512](f32) + bias) -> out bf16 [64][512]
// ---------------------------------------------------------------------------
__global__ __launch_bounds__(256, 1) void gemm_tanh_kernel(
    const unsigned short* __restrict__ A, const float* __restrict__ W,
    const float* __restrict__ bias, unsigned short* __restrict__ out)
{
    const int tid = threadIdx.x, lane = tid & 63, wave = tid >> 6;
    const int quad = lane >> 4, l16 = lane & 15;
    const int col = blockIdx.x * 16 + l16;
    bf16x8 Bw[16];
#pragma unroll
    for (int kt = 0; kt < 16; ++kt)
#pragma unroll
        for (int i = 0; i < 8; ++i)
            Bw[kt][i] = f2b(W[(size_t)(kt * 32 + quad * 8 + i) * HID + col]);
    f32x4 acc = {0.f, 0.f, 0.f, 0.f};
#pragma unroll
    for (int kt = 0; kt < 16; ++kt) {
        bf16x8 a = *(const bf16x8*)(A + (size_t)(wave * 16 + l16) * HID + kt * 32 + quad * 8);
        acc = __builtin_amdgcn_mfma_f32_16x16x32_bf16(a, Bw[kt], acc, 0, 0, 0);
    }
    const float bvv = bias[col];
#pragma unroll
    for (int r = 0; r < 4; ++r) {
        float y = fast_tanh(acc[r] + bvv);
        out[(size_t)(wave * 16 + quad * 4 + r) * HID + col] = (unsigned short)f2b(y);
    }
}

// ---------------------------------------------------------------------------
// logits = A[64x512](bf16) @ W3[512x50257](f32) + b3 -> f32 [64][50257]
// LDS-staged W3 tiles: coalesced float4 HBM reads.
// ---------------------------------------------------------------------------
__global__ __launch_bounds__(256, 2) void logits_kernel(
    const unsigned short* __restrict__ A, const float* __restrict__ W3,
    const float* __restrict__ b3, float* __restrict__ outL)
{
    const int tid = threadIdx.x, lane = tid & 63, wave = tid >> 6;
    const int quad = lane >> 4, l16 = lane & 15;
    const int c0 = blockIdx.x * 64;
    const int col = c0 + wave * 16 + l16;
    const bool cok = col < VOCAB;
    const int colc = cok ? col : (VOCAB - 1);

    __shared__ unsigned short wt[256][68];

    f32x4 acc[4];
#pragma unroll
    for (int rt = 0; rt < 4; ++rt) acc[rt] = (f32x4){0.f, 0.f, 0.f, 0.f};

    const int kr = tid >> 4;
    const int cg = (tid & 15) * 4;

    for (int kc = 0; kc < 2; ++kc) {
#pragma unroll 4
        for (int it = 0; it < 16; ++it) {
            const int k = it * 16 + kr;
            const int gc = c0 + cg;
            float4 wv;
            if (gc + 3 < VOCAB) {
                wv = *(const float4*)&W3[(size_t)(kc * 256 + k) * VOCAB + gc];
            } else {
                const float* Wr = &W3[(size_t)(kc * 256 + k) * VOCAB];
                wv.x = (gc + 0 < VOCAB) ? Wr[gc + 0] : 0.f;
                wv.y = (gc + 1 < VOCAB) ? Wr[gc + 1] : 0.f;
                wv.z = (gc + 2 < VOCAB) ? Wr[gc + 2] : 0.f;
                wv.w = (gc + 3 < VOCAB) ? Wr[gc + 3] : 0.f;
            }
            unsigned short* d = &wt[k][cg];
            d[0] = (unsigned short)f2b(wv.x);
            d[1] = (unsigned short)f2b(wv.y);
            d[2] = (unsigned short)f2b(wv.z);
            d[3] = (unsigned short)f2b(wv.w);
        }
        __syncthreads();
        bf16x8 Bw[8];
#pragma unroll
        for (int kt = 0; kt < 8; ++kt)
#pragma unroll
            for (int i = 0; i < 8; ++i)
                Bw[kt][i] = (short)wt[kt * 32 + quad * 8 + i][wave * 16 + l16];
#pragma unroll
        for (int rt = 0; rt < 4; ++rt)
#pragma unroll
            for (int kt = 0; kt < 8; ++kt) {
                bf16x8 a = *(const bf16x8*)(A + (size_t)(rt * 16 + l16) * HID +
                                            kc * 256 + kt * 32 + quad * 8);
                acc[rt] = __builtin_amdgcn_mfma_f32_16x16x32_bf16(a, Bw[kt], acc[rt], 0, 0, 0);
            }
        __syncthreads();
    }
    const float bvv = b3[colc];
    if (cok) {
#pragma unroll
        for (int rt = 0; rt < 4; ++rt)
#pragma unroll
            for (int r = 0; r < 4; ++r)
                outL[(size_t)(rt * 16 + quad * 4 + r) * VOCAB + col] = acc[rt][r] + bvv;
    }
}

// ---------------------------------------------------------------------------
// row-wise log_softmax over [64][50257], float4 main loop
// ---------------------------------------------------------------------------
__global__ __launch_bounds__(256, 1) void lsm_kernel(
    const float* __restrict__ lg, float* __restrict__ out)
{
    const int row = blockIdx.x;
    const float* L = lg + (size_t)row * VOCAB;
    const float4* L4 = (const float4*)L;
    const int nv4 = VOCAB / 4;

    float m = -1e30f;
    for (int i = threadIdx.x; i < nv4; i += 256) {
        float4 v = L4[i];
        m = fmaxf(fmaxf(fmaxf(m, v.x), fmaxf(v.y, v.z)), v.w);
    }
    if (threadIdx.x == 0) m = fmaxf(m, L[VOCAB - 1]);
#pragma unroll
    for (int o = 32; o; o >>= 1) m = fmaxf(m, __shfl_xor(m, o));
    __shared__ float red[4], red2[4];
    if ((threadIdx.x & 63) == 0) red[threadIdx.x >> 6] = m;
    __syncthreads();
    m = fmaxf(fmaxf(red[0], red[1]), fmaxf(red[2], red[3]));

    float s = 0.f;
    for (int i = threadIdx.x; i < nv4; i += 256) {
        float4 v = L4[i];
        s += __expf(v.x - m) + __expf(v.y - m) + __expf(v.z - m) + __expf(v.w - m);
    }
    if (threadIdx.x == 0) s += __expf(L[VOCAB - 1] - m);
#pragma unroll
    for (int o = 32; o; o >>= 1) s += __shfl_xor(s, o);
    if ((threadIdx.x & 63) == 0) red2[threadIdx.x >> 6] = s;
    __syncthreads();
    s = red2[0] + red2[1] + red2[2] + red2[3];
    const float ls = m + __logf(s);

    float* O = out + (size_t)row * VOCAB;
    float4* O4 = (float4*)O;
    for (int i = threadIdx.x; i < nv4; i += 256) {
        float4 v = L4[i];
        O4[i] = (float4){v.x - ls, v.y - ls, v.z - ls, v.w - ls};
    }
    if (threadIdx.x == 0) O[VOCAB - 1] = L[VOCAB - 1] - ls;
}

extern "C" void kernel_launch(void* const* d_in, const int* in_sizes, int n_in,
                              void* d_out, int out_size, void* d_ws, size_t ws_size,
                              hipStream_t stream) {
    (void)in_sizes; (void)n_in; (void)out_size; (void)ws_size;
    const int*   idx = (const int*)d_in[0];
    const float* emb = (const float*)d_in[1];
    const float* Wi  = (const float*)d_in[2];
    const float* Wh  = (const float*)d_in[3];
    const float* b   = (const float*)d_in[4];
    const float* W1  = (const float*)d_in[5];
    const float* b1  = (const float*)d_in[6];
    const float* W2  = (const float*)d_in[7];
    const float* b2  = (const float*)d_in[8];
    const float* W3  = (const float*)d_in[9];
    const float* b3  = (const float*)d_in[10];
    float* out = (float*)d_out;

    // ws layout (time-disjoint aliasing, 13.13 MB total):
    //   [0, 256K)           hbuf   (lstm only) -- later reused by y1/y2
    //   [0, 64K)            y1     (gemm1 out / gemm2 in)
    //   [64K, 128K)         y2     (gemm2 out / logits in)
    //   [256K, 320K)        hfinal (lstm out / gemm1 in) -- dead before logits writes
    //   [256K, 256K+12.87M) logits (logits out / lsm in)
    char* w = (char*)d_ws;
    unsigned long long* hbuf   = (unsigned long long*)w;
    unsigned short*     y1     = (unsigned short*)w;
    unsigned short*     y2     = (unsigned short*)(w + 65536);
    unsigned short*     hfinal = (unsigned short*)(w + 262144);
    float*              logits = (float*)(w + 262144);

    lstm_kernel<<<128, 256, 0, stream>>>(idx, emb, Wi, Wh, b, hbuf, hfinal);
    gemm_tanh_kernel<<<HID / 16, 256, 0, stream>>>(hfinal, W1, b1, y1);
    gemm_tanh_kernel<<<HID / 16, 256, 0, stream>>>(y1, W2, b2, y2);
    logits_kernel<<<(VOCAB + 63) / 64, 256, 0, stream>>>(y2, W3, b3, logits);
    lsm_kernel<<<BATCH, 256, 0, stream>>>(logits, out);
}